// Round 1
// baseline (214.914 us; speedup 1.0000x reference)
//
#include <hip/hip_runtime.h>

// Problem constants (fixed by the reference: XSIZE=128, B=8, N=262144)
constexpr unsigned XS         = 128;
constexpr unsigned NB         = 8;
constexpr unsigned NPTS       = 262144;        // 2^18 points per batch
constexpr unsigned GRID_ELEMS = 1u << 21;      // 128^3 voxels per batch
constexpr unsigned TOTAL_PTS  = NB * NPTS;     // 2^21

// d_ws layout: [ grids: 8 * 2^21 floats = 64 MiB ][ staging: 16 slots * 16 floats = 1 KiB ]
constexpr size_t GRID_FLOATS  = (size_t)NB * GRID_ELEMS;   // 16,777,216
constexpr size_t STAGE_FLOATS = 16 * 16;                   // padded: 1 float per 64B line

// ---------------------------------------------------------------------------
// Kernel 1: scatter-add point values into per-batch 128^3 grids.
// One thread per point. Random addresses over 16.7M voxels -> low contention.
__global__ __launch_bounds__(256) void scatter_add_kernel(
        const int* __restrict__ idx, const float* __restrict__ vals,
        float* __restrict__ grid) {
    unsigned t = blockIdx.x * 256u + threadIdx.x;     // < 2^21
    unsigned b = t >> 18;                             // batch
    const int* p = idx + 3ull * t;
    unsigned i = (unsigned)p[0], j = (unsigned)p[1], k = (unsigned)p[2];
    float v = vals[t];
    unsigned off = (b << 21) + (i << 14) + (j << 7) + k;
    atomicAdd(grid + off, v);
}

// ---------------------------------------------------------------------------
// Kernel 2: TV + MSE over axis-adjacent diffs.
// One thread per 16-float k-chunk of a (b,i,j) row: 8 chunks/row.
// Thread mapping: t = (b, ij, q) with q fastest -> a wave64 covers 8 full rows
// (3 x 4KB footprint, fits L1; 3/4 of the float4 loads hit L1).
__global__ __launch_bounds__(256) void tv_mse_kernel(
        const float* __restrict__ grid, float* __restrict__ stage) {
    unsigned t  = blockIdx.x * 256u + threadIdx.x;    // < 2^20
    unsigned b  = t >> 17;                            // 131072 threads / batch (512 blocks, aligned)
    unsigned r  = t & 0x1FFFFu;
    unsigned q  = r & 7u;                             // k-chunk: k0 = q*16
    unsigned ij = r >> 3;                             // 0..16383
    unsigned i  = ij >> 7, j = ij & 127u;

    const float* rc = grid + ((size_t)b << 21) + ((size_t)ij << 7) + (q << 4);

    float4 c0 = ((const float4*)rc)[0];
    float4 c1 = ((const float4*)rc)[1];
    float4 c2 = ((const float4*)rc)[2];
    float4 c3 = ((const float4*)rc)[3];

    float tv = 0.f, mse = 0.f;
    auto acc4 = [&](float4 a, float4 c) {
        float d0 = a.x - c.x, d1 = a.y - c.y, d2 = a.z - c.z, d3 = a.w - c.w;
        tv  += fabsf(d0) + fabsf(d1) + fabsf(d2) + fabsf(d3);
        mse += d0 * d0 + d1 * d1 + d2 * d2 + d3 * d3;
    };

    // d1: diff along i (row i+1 is 128*128 floats away)
    if (i < 127u) {
        const float4* ra = (const float4*)(rc + XS * XS);
        acc4(ra[0], c0); acc4(ra[1], c1); acc4(ra[2], c2); acc4(ra[3], c3);
    }
    // d2: diff along j (row j+1 is 128 floats away)
    if (j < 127u) {
        const float4* rb = (const float4*)(rc + XS);
        acc4(rb[0], c0); acc4(rb[1], c1); acc4(rb[2], c2); acc4(rb[3], c3);
    }
    // d3: diff along k within the chunk (+ seam element from the next chunk)
    float cs[16] = {c0.x, c0.y, c0.z, c0.w, c1.x, c1.y, c1.z, c1.w,
                    c2.x, c2.y, c2.z, c2.w, c3.x, c3.y, c3.z, c3.w};
#pragma unroll
    for (int n = 0; n < 15; ++n) {
        float d = cs[n + 1] - cs[n];
        tv += fabsf(d); mse += d * d;
    }
    if (q < 7u) {                       // seam: c[k0+16] - c[k0+15]
        float nx = rc[16];
        float d = nx - cs[15];
        tv += fabsf(d); mse += d * d;
    }

    // Block reduction: wave64 shuffle, then LDS across the 4 waves.
#pragma unroll
    for (int o = 32; o > 0; o >>= 1) {
        tv  += __shfl_down(tv, o, 64);
        mse += __shfl_down(mse, o, 64);
    }
    __shared__ float sred[8];
    unsigned lane = threadIdx.x & 63u, w = threadIdx.x >> 6;
    if (lane == 0) { sred[w] = tv; sred[4 + w] = mse; }
    __syncthreads();
    if (threadIdx.x == 0) {
        float tt = sred[0] + sred[1] + sred[2] + sred[3];
        float mm = sred[4] + sred[5] + sred[6] + sred[7];
        // Padded staging: slot s occupies stage[s*16] (one 64B line per slot).
        // Slot order matches d_out: [0..7]=tv per batch, [8..15]=mse per batch.
        atomicAdd(stage + (size_t)b * 16u,        tt);
        atomicAdd(stage + (size_t)(8u + b) * 16u, mm);
    }
}

// ---------------------------------------------------------------------------
// Kernel 3: scale staged sums into d_out (and overwrite the 0xAA poison).
__global__ void finalize_kernel(const float* __restrict__ stage,
                                float* __restrict__ out) {
    unsigned i = threadIdx.x;
    if (i < 16u) {
        float s = stage[i * 16u];
        float scale = (i < 8u) ? (1.0f / 2097152.0f)   // / xsize^3
                               : (1.0f / 32512.0f);    // / (2*128^2 - 2*128)
        out[i] = s * scale;
    }
}

// ---------------------------------------------------------------------------
extern "C" void kernel_launch(void* const* d_in, const int* in_sizes, int n_in,
                              void* d_out, int out_size, void* d_ws, size_t ws_size,
                              hipStream_t stream) {
    const int*   idx  = (const int*)d_in[0];    // [8, 262144, 3] int32
    const float* vals = (const float*)d_in[1];  // [8, 262144] float32
    // d_in[2] = xsize (always 128; baked into constants)

    float* grid  = (float*)d_ws;
    float* stage = grid + GRID_FLOATS;
    float* out   = (float*)d_out;

    // Zero grids + staging (d_ws is re-poisoned to 0xAA before every call).
    hipMemsetAsync(d_ws, 0, (GRID_FLOATS + STAGE_FLOATS) * sizeof(float), stream);

    scatter_add_kernel<<<TOTAL_PTS / 256, 256, 0, stream>>>(idx, vals, grid);
    tv_mse_kernel<<<(NB * 131072u) / 256, 256, 0, stream>>>(grid, stage);
    finalize_kernel<<<1, 64, 0, stream>>>(stage, out);
}